// Round 6
// baseline (864.051 us; speedup 1.0000x reference)
//
#include <hip/hip_runtime.h>
#include <cstdint>
#include <cstddef>

#define B_ 4
#define L_ 4096
#define H_ 1024
#define NH_ 16
#define W_ 64
#define SHIFT_ 32
#define FF_ 4096
#define HD_ 64

typedef unsigned short u16;
typedef __attribute__((ext_vector_type(8))) __bf16 bf16x8;
typedef __attribute__((ext_vector_type(4))) float f32x4;
typedef __attribute__((ext_vector_type(4))) unsigned short u16x4;

__device__ __forceinline__ float bf2f(u16 u) {
    unsigned int x = ((unsigned int)u) << 16;
    float f;
    __builtin_memcpy(&f, &x, 4);
    return f;
}
__device__ __forceinline__ u16 f2bf(float f) {
    unsigned int u;
    __builtin_memcpy(&u, &f, 4);
    u = (u + 0x7fffu + ((u >> 16) & 1u)) >> 16;  // RNE
    return (u16)u;
}

__device__ __forceinline__ void gload16(const u16* g, u16* l) {
    __builtin_amdgcn_global_load_lds(
        (const __attribute__((address_space(1))) void*)g,
        (__attribute__((address_space(3))) void*)l, 16, 0, 0);
}

__device__ __forceinline__ bf16x8 ldfrag(const u16* p) {
    uint4 v = *(const uint4*)p;  // ds_read_b128
    bf16x8 r;
    __builtin_memcpy(&r, &v, 16);
    return r;
}

__device__ __forceinline__ f32x4 mfma16(bf16x8 a, bf16x8 b, f32x4 c) {
    return __builtin_amdgcn_mfma_f32_16x16x32_bf16(a, b, c, 0, 0, 0);
}

// ---------------------------------------------------------------------------
// fp32 -> bf16 conversion (weights prologue)
// ---------------------------------------------------------------------------
__global__ __launch_bounds__(256) void cvt_kernel(
    const float* __restrict__ src, u16* __restrict__ dst, int n4) {
    const int i = blockIdx.x * 256 + threadIdx.x;
    if (i < n4) {
        const float4 v = ((const float4*)src)[i];
        u16x4 o;
        o[0] = f2bf(v.x); o[1] = f2bf(v.y);
        o[2] = f2bf(v.z); o[3] = f2bf(v.w);
        ((u16x4*)dst)[i] = o;
    }
}

// ---------------------------------------------------------------------------
// GEMM 256x256 tile, BK=64, 512 threads (8 waves, 2Mx4N), 16x16x32 MFMA.
// 2-phase schedule per K-tile, 4 barriers + 2 lgkm-drains (R3 had 8+4);
// fragment addressing byte-identical to the verified R3:
//   p0: [12 reads kk0][STG B(t+1)->other dbuf][BAR][lgk0+schedbar]
//       [setprio1 32 MFMA setprio0]
//   p1: [12 reads kk1][BAR][lgk0+schedbar][setprio1 32 MFMA setprio0]
//   [BAR]  <- SEAL: follows every wave's lgkmcnt(0) drain of kk1 reads,
//             so the A-overwrite below is barrier-proof (R3 discipline,
//             not just DMA-latency-safe)
//   [STG A(t+2)->cur dbuf][vmcnt(4)][BAR]
// Race audit: B-stage target's last reads sealed 2 barriers ago (prev tile
// p1 + boundary); A-stage target's reads sealed by the SEAL barrier above.
// vmcnt: steady outstanding at boundary = A(t+1)+B(t+1)+A(t+2) = 12 ->
// wait to 4 (drains A(t+1),B(t+1); keeps A(t+2) in flight). Drain to 0
// only when t+2 >= nt. Never vmcnt(0) mid-loop otherwise.
// LDS per dbuf: [256 rows][8 slots of 16B], slot' = slot ^ (row&7); linear
// DMA dest + inverse-swizzled global source (both-sides rule).
// XCD-aware chunked blockIdx swizzle (T1).
// Epilogue: acc -> LDS (dead staging buffers) -> coalesced dwordx4 stores;
//   F32OUT: C fp32 accumulated in place (C += result), 64B/quad RMW.
// ---------------------------------------------------------------------------
template <int GELU, int BIAS, int F32OUT>
__global__ __launch_bounds__(512, 2) void gemm256(
    const u16* __restrict__ A, const u16* __restrict__ Bm,
    int lda, int ldb, const float* __restrict__ bias,
    void* __restrict__ Cv, int N, int K) {
    __shared__ __align__(16) u16 sA0[16384];
    __shared__ __align__(16) u16 sA1[16384];
    __shared__ __align__(16) u16 sB0[16384];
    __shared__ __align__(16) u16 sB1[16384];

    const int tid = threadIdx.x;
    const int lane = tid & 63;
    const int wv = tid >> 6;
    const int wr = wv >> 2;      // 0..1  (M half: 128 rows)
    const int wc = wv & 3;       // 0..3  (N quarter: 64 cols)
    const int ln15 = lane & 15;
    const int quad = lane >> 4;  // 0..3

    // XCD-aware chunked swizzle (all our grids have nwg % 8 == 0)
    const int gX = gridDim.x;
    const int nwg = gX * gridDim.y;
    int lin = blockIdx.y * gX + blockIdx.x;
    if ((nwg & 7) == 0) lin = (lin & 7) * (nwg >> 3) + (lin >> 3);
    const int mBase = (lin / gX) * 256;
    const int nBase = (lin % gX) * 256;
    const int nt = K >> 6;  // 16 or 32 for our shapes (even)

    // staging: thread -> (row srow, dest slot tid&7); global k-chunk inverse-
    // swizzled so the linear DMA dest yields the swizzled layout.
    const int srow = tid >> 3;                    // 0..63
    const int sk = ((tid & 7) ^ (srow & 7)) * 8;  // u16 units
    const u16* gA = A + (size_t)(mBase + srow) * lda + sk;
    const u16* gB = Bm + (size_t)(nBase + srow) * ldb + sk;

    // read offsets (u16 units): frag(f,kk) @ rb + f*1024 + swK
    const int rbA = (wr * 128 + ln15) * 64;
    const int rbB = (wc * 64 + ln15) * 64;
    const int sw0 = (quad ^ (ln15 & 7)) * 8;        // kk=0
    const int sw1 = ((4 + quad) ^ (ln15 & 7)) * 8;  // kk=1

    f32x4 acc[8][4] = {};

#define STG(gp, ld, buf, h, t)                                      \
    do {                                                            \
        const u16* _g = (gp) + (size_t)((h)*128) * (ld) + (t) * 64; \
        u16* _d = (buf) + (h)*8192 + tid * 8;                       \
        gload16(_g, _d);                                            \
        gload16(_g + (size_t)64 * (ld), _d + 4096);                 \
    } while (0)
#define LGK0                                           \
    asm volatile("s_waitcnt lgkmcnt(0)" ::: "memory"); \
    __builtin_amdgcn_sched_barrier(0)
#define VMC4 asm volatile("s_waitcnt vmcnt(4)" ::: "memory")
#define VMC0 asm volatile("s_waitcnt vmcnt(0)" ::: "memory")
#define BAR __builtin_amdgcn_s_barrier()

#define TILE2(CA, CB, OB, t)                                        \
    do {                                                            \
        bf16x8 a0[8], a1[8], b0[4], b1[4];                          \
        /* p0: all kk0 reads (12); stage (t+1).B -> other dbuf */   \
        _Pragma("unroll") for (int fm = 0; fm < 8; ++fm)            \
            a0[fm] = ldfrag((CA) + rbA + fm * 1024 + sw0);          \
        _Pragma("unroll") for (int fn = 0; fn < 4; ++fn)            \
            b0[fn] = ldfrag((CB) + rbB + fn * 1024 + sw0);          \
        if ((t) + 1 < nt) {                                         \
            STG(gB, ldb, OB, 0, (t) + 1);                           \
            STG(gB, ldb, OB, 1, (t) + 1);                           \
        }                                                           \
        BAR;                                                        \
        LGK0;                                                       \
        __builtin_amdgcn_s_setprio(1);                              \
        _Pragma("unroll") for (int fm = 0; fm < 8; ++fm)            \
            _Pragma("unroll") for (int fn = 0; fn < 4; ++fn)        \
                acc[fm][fn] = mfma16(a0[fm], b0[fn], acc[fm][fn]);  \
        __builtin_amdgcn_s_setprio(0);                              \
        /* p1: all kk1 reads (12); latency hides under MFMA0 */     \
        _Pragma("unroll") for (int fm = 0; fm < 8; ++fm)            \
            a1[fm] = ldfrag((CA) + rbA + fm * 1024 + sw1);          \
        _Pragma("unroll") for (int fn = 0; fn < 4; ++fn)            \
            b1[fn] = ldfrag((CB) + rbB + fn * 1024 + sw1);          \
        BAR;                                                        \
        LGK0;                                                       \
        __builtin_amdgcn_s_setprio(1);                              \
        _Pragma("unroll") for (int fm = 0; fm < 8; ++fm)            \
            _Pragma("unroll") for (int fn = 0; fn < 4; ++fn)        \
                acc[fm][fn] = mfma16(a1[fm], b1[fn], acc[fm][fn]);  \
        __builtin_amdgcn_s_setprio(0);                              \
        BAR; /* SEAL: all waves' kk1 reads drained before overwrite */ \
        if ((t) + 2 < nt) {                                         \
            STG(gA, lda, CA, 0, (t) + 2);                           \
            STG(gA, lda, CA, 1, (t) + 2);                           \
            VMC4;                                                   \
        } else {                                                    \
            VMC0;                                                   \
        }                                                           \
        BAR;                                                        \
    } while (0)

    // prologue: t0.A, t0.B, t1.A (12 loads); vmcnt(4): t0 resident,
    // t1.A stays in flight.
    STG(gA, lda, sA0, 0, 0);
    STG(gA, lda, sA0, 1, 0);
    STG(gB, ldb, sB0, 0, 0);
    STG(gB, ldb, sB0, 1, 0);
    STG(gA, lda, sA1, 0, 1);
    STG(gA, lda, sA1, 1, 1);
    VMC4;
    BAR;

    for (int t = 0; t < nt; t += 2) {
        TILE2(sA0, sB0, sB1, t);
        TILE2(sA1, sB1, sB0, t + 1);
    }

    if (F32OUT) {
        // fp32 accumulate in place: each quad writes 64B contiguous.
        float* C = (float*)Cv;
        const int r0 = mBase + wr * 128 + quad * 4;
        const int c0 = nBase + wc * 64 + ln15;
#pragma unroll
        for (int fn = 0; fn < 4; ++fn) {
            const int col = c0 + fn * 16;
            const float bcol = BIAS ? bias[col] : 0.0f;
#pragma unroll
            for (int fm = 0; fm < 8; ++fm) {
#pragma unroll
                for (int r = 0; r < 4; ++r) {
                    const int row = r0 + fm * 16 + r;
                    float v = acc[fm][fn][r] + bcol;
                    if (GELU) v = 0.5f * v * (1.0f + erff(v * 0.70710678118f));
                    C[(size_t)row * N + col] += v;
                }
            }
        }
    } else {
        // stage C tile in LDS (rows 0-63:sA0, 64-127:sA1, 128-191:sB0,
        // 192-255:sB1), then fully-coalesced dwordx4 stores.
        u16* lo = wr ? sB0 : sA0;  // fm 0..3
        u16* hi = wr ? sB1 : sA1;  // fm 4..7
#pragma unroll
        for (int fn = 0; fn < 4; ++fn) {
            const int col = wc * 64 + fn * 16 + ln15;
            const float bcol = BIAS ? bias[nBase + col] : 0.0f;
#pragma unroll
            for (int fm = 0; fm < 8; ++fm) {
                u16* wb = (fm < 4) ? lo : hi;
#pragma unroll
                for (int r = 0; r < 4; ++r) {
                    float v = acc[fm][fn][r] + bcol;
                    if (GELU) v = 0.5f * v * (1.0f + erff(v * 0.70710678118f));
                    wb[((fm & 3) * 16 + quad * 4 + r) * 256 + col] = f2bf(v);
                }
            }
        }
        __syncthreads();
        u16* Cu = (u16*)Cv;
        const int rr = tid >> 5;        // 0..15
        const int cc = (tid & 31) * 8;  // u16 units, 16B chunks
#pragma unroll
        for (int p = 0; p < 16; ++p) {
            const u16* rb = (p < 4) ? sA0 : (p < 8) ? sA1 : (p < 12) ? sB0 : sB1;
            const uint4 vv = *(const uint4*)(rb + ((p & 3) * 16 + rr) * 256 + cc);
            *(uint4*)(Cu + (size_t)(mBase + p * 16 + rr) * N + nBase + cc) = vv;
        }
    }
#undef TILE2
#undef BAR
#undef VMC0
#undef VMC4
#undef LGK0
#undef STG
}

// ---------------------------------------------------------------------------
// LN1 (full M): y[r,:] = bf16( LN(x[bi,(l+SHIFT)%L,:]) * g + b ), fp32 input
// ---------------------------------------------------------------------------
__global__ __launch_bounds__(256, 4) void ln1_kernel(
    const float* __restrict__ x, const float* __restrict__ g,
    const float* __restrict__ bb, u16* __restrict__ y) {
    const int row = blockIdx.x;
    const int bi = row >> 12, l = row & 4095;
    const float* src = x + ((size_t)(bi << 12) + ((l + SHIFT_) & 4095)) * 1024;
    const int t = threadIdx.x;
    const int lane = t & 63, wv = t >> 6;

    const float4 u = ((const float4*)src)[t];
    float v[4] = {u.x, u.y, u.z, u.w};
    float sum = 0.f, sq = 0.f;
#pragma unroll
    for (int k = 0; k < 4; ++k) { sum += v[k]; sq += v[k] * v[k]; }
    for (int off = 32; off > 0; off >>= 1) {
        sum += __shfl_down(sum, off);
        sq += __shfl_down(sq, off);
    }
    __shared__ float red[8];
    __shared__ float smu, srs;
    if (lane == 0) { red[wv] = sum; red[4 + wv] = sq; }
    __syncthreads();
    if (t == 0) {
        float s = red[0] + red[1] + red[2] + red[3];
        float q = red[4] + red[5] + red[6] + red[7];
        float mu = s * (1.0f / 1024.0f);
        float var = q * (1.0f / 1024.0f) - mu * mu;
        smu = mu;
        srs = rsqrtf(var + 1e-5f);
    }
    __syncthreads();
    const float mu = smu, rs = srs;
    const float4 gv = ((const float4*)g)[t];
    const float4 bv = ((const float4*)bb)[t];
    u16x4 outv;
    outv[0] = f2bf((v[0] - mu) * rs * gv.x + bv.x);
    outv[1] = f2bf((v[1] - mu) * rs * gv.y + bv.y);
    outv[2] = f2bf((v[2] - mu) * rs * gv.z + bv.z);
    outv[3] = f2bf((v[3] - mu) * rs * gv.w + bv.w);
    ((u16x4*)(y + (size_t)row * 1024))[t] = outv;
}

// ---------------------------------------------------------------------------
// LN2 fused (full M): x2 = x + roll(o2,+32)  (fp32 -> d_out)
//                     z  = bf16( LN(x2)*g + b )
// ---------------------------------------------------------------------------
__global__ __launch_bounds__(256, 4) void ln2_kernel(
    const float* __restrict__ x, const u16* __restrict__ o2,
    const float* __restrict__ g, const float* __restrict__ bb,
    float* __restrict__ x2, u16* __restrict__ z) {
    const int row = blockIdx.x;
    const int bi = row >> 12, l = row & 4095;
    const size_t srcO = (size_t)(bi << 12) + ((l - SHIFT_) & 4095);
    const int t = threadIdx.x;
    const int lane = t & 63, wv = t >> 6;

    const float4 ux = ((const float4*)(x + (size_t)row * 1024))[t];
    const u16x4 uo = ((const u16x4*)(o2 + srcO * 1024))[t];
    float v[4];
    v[0] = ux.x + bf2f(uo[0]);
    v[1] = ux.y + bf2f(uo[1]);
    v[2] = ux.z + bf2f(uo[2]);
    v[3] = ux.w + bf2f(uo[3]);
    float sum = 0.f, sq = 0.f;
#pragma unroll
    for (int k = 0; k < 4; ++k) { sum += v[k]; sq += v[k] * v[k]; }
    float4 x2v = {v[0], v[1], v[2], v[3]};
    ((float4*)(x2 + (size_t)row * 1024))[t] = x2v;

    for (int off = 32; off > 0; off >>= 1) {
        sum += __shfl_down(sum, off);
        sq += __shfl_down(sq, off);
    }
    __shared__ float red[8];
    __shared__ float smu, srs;
    if (lane == 0) { red[wv] = sum; red[4 + wv] = sq; }
    __syncthreads();
    if (t == 0) {
        float s = red[0] + red[1] + red[2] + red[3];
        float q = red[4] + red[5] + red[6] + red[7];
        float mu = s * (1.0f / 1024.0f);
        float var = q * (1.0f / 1024.0f) - mu * mu;
        smu = mu;
        srs = rsqrtf(var + 1e-5f);
    }
    __syncthreads();
    const float mu = smu, rs = srs;
    const float4 gv = ((const float4*)g)[t];
    const float4 bv = ((const float4*)bb)[t];
    u16x4 outv;
    outv[0] = f2bf((v[0] - mu) * rs * gv.x + bv.x);
    outv[1] = f2bf((v[1] - mu) * rs * gv.y + bv.y);
    outv[2] = f2bf((v[2] - mu) * rs * gv.z + bv.z);
    outv[3] = f2bf((v[3] - mu) * rs * gv.w + bv.w);
    ((u16x4*)(z + (size_t)row * 1024))[t] = outv;
}

// ---------------------------------------------------------------------------
// Windowed attention (bf16 in/out): block = (window, head).
// ---------------------------------------------------------------------------
__global__ __launch_bounds__(256, 2) void attn_kernel(
    const u16* __restrict__ qkv, u16* __restrict__ o) {
    __shared__ __align__(16) u16 sQ[64 * 64];  // reused as P
    __shared__ __align__(16) u16 sK[64 * 64];
    __shared__ __align__(16) u16 sV[64 * 64];
    __shared__ float sS[64 * 66];

    const int t = threadIdx.x;
    const int win = blockIdx.x >> 4;
    const int head = blockIdx.x & 15;
    const size_t rowbase = (size_t)win * 64;
    const u16* base = qkv + rowbase * 3072 + head * 64;

    {  // stage Q,K,V via global_load_lds: chunks c = t, t+256
        const int c0 = t, c1 = t + 256;
        const int r0 = c0 >> 3, d0 = (c0 & 7) * 8;
        const int r1 = c1 >> 3, d1 = (c1 & 7) * 8;
        const u16* g0 = base + (size_t)r0 * 3072 + d0;
        const u16* g1 = base + (size_t)r1 * 3072 + d1;
        gload16(g0, &sQ[c0 * 8]);
        gload16(g1, &sQ[c1 * 8]);
        gload16(g0 + 1024, &sK[c0 * 8]);
        gload16(g1 + 1024, &sK[c1 * 8]);
        gload16(g0 + 2048, &sV[c0 * 8]);
        gload16(g1 + 2048, &sV[c1 * 8]);
    }
    __syncthreads();

    const int lane = t & 63, wv = t >> 6;
    const int ln15 = lane & 15, quad = lane >> 4;

    f32x4 accS[4] = {};
#pragma unroll
    for (int kb = 0; kb < 2; ++kb) {
        bf16x8 aF = ldfrag(&sQ[(wv * 16 + ln15) * 64 + kb * 32 + quad * 8]);
#pragma unroll
        for (int jt = 0; jt < 4; ++jt) {
            bf16x8 bF = ldfrag(&sK[(jt * 16 + ln15) * 64 + kb * 32 + quad * 8]);
            accS[jt] = mfma16(aF, bF, accS[jt]);
        }
    }
#pragma unroll
    for (int jt = 0; jt < 4; ++jt)
#pragma unroll
        for (int r = 0; r < 4; ++r)
            sS[(wv * 16 + quad * 4 + r) * 66 + jt * 16 + ln15] =
                accS[jt][r] * 0.125f;
    __syncthreads();

    {
        const int row = t >> 2, part = t & 3;
        const float* sr = &sS[row * 66 + part * 16];
        float vals[16];
        float mx = -1e30f;
#pragma unroll
        for (int i = 0; i < 16; ++i) {
            vals[i] = sr[i];
            mx = fmaxf(mx, vals[i]);
        }
        mx = fmaxf(mx, __shfl_xor(mx, 1));
        mx = fmaxf(mx, __shfl_xor(mx, 2));
        float sum = 0.f;
#pragma unroll
        for (int i = 0; i < 16; ++i) {
            vals[i] = __expf(vals[i] - mx);
            sum += vals[i];
        }
        sum += __shfl_xor(sum, 1);
        sum += __shfl_xor(sum, 2);
        const float inv = 1.0f / sum;
        u16* pr = &sQ[row * 64 + part * 16];
#pragma unroll
        for (int i = 0; i < 16; ++i) pr[i] = f2bf(vals[i] * inv);
    }
    __syncthreads();

    f32x4 accO[4] = {};
#pragma unroll
    for (int kb = 0; kb < 2; ++kb) {
        bf16x8 aF = ldfrag(&sQ[(wv * 16 + ln15) * 64 + kb * 32 + quad * 8]);
#pragma unroll
        for (int dt = 0; dt < 4; ++dt) {
            u16 tmp[8];
#pragma unroll
            for (int j = 0; j < 8; ++j)
                tmp[j] = sV[(kb * 32 + quad * 8 + j) * 64 + dt * 16 + ln15];
            bf16x8 bF;
            __builtin_memcpy(&bF, tmp, 16);
            accO[dt] = mfma16(aF, bF, accO[dt]);
        }
    }
    u16* ob = o + rowbase * 1024 + head * 64;
#pragma unroll
    for (int dt = 0; dt < 4; ++dt)
#pragma unroll
        for (int r = 0; r < 4; ++r) {
            const int q = wv * 16 + quad * 4 + r;
            const int d = dt * 16 + ln15;
            ob[(size_t)q * 1024 + d] = f2bf(accO[dt][r]);
        }
}

// ---------------------------------------------------------------------------
extern "C" void kernel_launch(void* const* d_in, const int* in_sizes, int n_in,
                              void* d_out, int out_size, void* d_ws,
                              size_t ws_size, hipStream_t stream) {
    (void)in_sizes; (void)n_in; (void)out_size; (void)ws_size;
    const float* x = (const float*)d_in[0];
    const float* ln1_g = (const float*)d_in[1];
    const float* ln1_b = (const float*)d_in[2];
    const float* in_proj_w = (const float*)d_in[3];
    const float* in_proj_b = (const float*)d_in[4];
    const float* out_proj_w = (const float*)d_in[5];
    const float* out_proj_b = (const float*)d_in[6];
    const float* ln2_g = (const float*)d_in[7];
    const float* ln2_b = (const float*)d_in[8];
    const float* w1 = (const float*)d_in[9];
    const float* b1 = (const float*)d_in[10];
    const float* w2 = (const float*)d_in[11];
    const float* b2 = (const float*)d_in[12];
    float* out = (float*)d_out;

    // Workspace layout (120 MB high-water; evidence: ws >= 160 MB):
    //   [  0,  8M) w1 bf16 (persist)     [  8, 16M) w2 bf16 (persist)
    //   [ 16, 22M) inproj bf16 (A)       [ 22, 24M) outproj bf16 (A)
    //   [ 24,120M) qkv bf16 full M (A, 16384 x 3072)
    //   [ 88,120M) o2 bf16 full M (out_proj -> ln2; overlays dead qkv tail)
    //   [ 16, 48M) z bf16 full M (B -> C; overlays dead inproj/outproj/qkv)
    //   [ 48,112M) h_half bf16 (C, 16384 x 2048; overlays dead qkv/o2)
    // d_out doubles as scratch: phase A qin [0,32M) + o_full [32,64M) bf16;
    // phase B writes x2 fp32 over all of d_out; FF2 epilogue RMW-accumulates
    // the two FF halves (+b2 on the second) directly into it.
    char* ws = (char*)d_ws;
    const size_t MB = 1024 * 1024;
    u16* wb_w1 = (u16*)(ws + 0 * MB);
    u16* wb_w2 = (u16*)(ws + 8 * MB);
    u16* wb_inproj = (u16*)(ws + 16 * MB);
    u16* wb_outproj = (u16*)(ws + 22 * MB);
    u16* qkv = (u16*)(ws + 24 * MB);
    u16* o2 = (u16*)(ws + 88 * MB);
    u16* z = (u16*)(ws + 16 * MB);
    u16* h_buf = (u16*)(ws + 48 * MB);

    u16* qin = (u16*)d_out;                        // [0,32M) of d_out
    u16* o_full = (u16*)((char*)d_out + 32 * MB);  // [32,64M) of d_out
    float* x2 = out;

    const int M = B_ * L_;  // 16384

    // Prologue: weights fp32 -> bf16
    cvt_kernel<<<(FF_ * H_ / 4 + 255) / 256, 256, 0, stream>>>(
        w1, wb_w1, FF_ * H_ / 4);
    cvt_kernel<<<(H_ * FF_ / 4 + 255) / 256, 256, 0, stream>>>(
        w2, wb_w2, H_ * FF_ / 4);
    cvt_kernel<<<(3 * H_ * H_ / 4 + 255) / 256, 256, 0, stream>>>(
        in_proj_w, wb_inproj, 3 * H_ * H_ / 4);
    cvt_kernel<<<(H_ * H_ / 4 + 255) / 256, 256, 0, stream>>>(
        out_proj_w, wb_outproj, H_ * H_ / 4);

    // Phase A (full M): ln1 -> qkv proj -> windowed attn -> out_proj
    ln1_kernel<<<M, 256, 0, stream>>>(x, ln1_g, ln1_b, qin);
    gemm256<0, 1, 0><<<dim3(3 * H_ / 256, M / 256), 512, 0, stream>>>(
        qin, wb_inproj, H_, H_, in_proj_b, qkv, 3 * H_, H_);
    attn_kernel<<<(M / W_) * NH_, 256, 0, stream>>>(qkv, o_full);
    gemm256<0, 1, 0><<<dim3(H_ / 256, M / 256), 512, 0, stream>>>(
        o_full, wb_outproj, H_, H_, out_proj_b, o2, H_, H_);

    // Phase B: x2 = x + roll(o2,+32) (fp32 -> d_out), z = bf16(LN2(x2))
    ln2_kernel<<<M, 256, 0, stream>>>(x, o2, ln2_g, ln2_b, x2, z);

    // Phase C: FFN split along hidden dim (2 halves of FF=2048), full M.
    //   FF1: h = gelu(z @ w1[hf]^T + b1[hf])   grid (8,64) = 512 blocks
    //   FF2: out += h @ w2[:,hf]^T (+b2 once)  grid (4,64) = 256 blocks, RMW
    gemm256<1, 1, 0><<<dim3(2048 / 256, M / 256), 512, 0, stream>>>(
        z, wb_w1, H_, H_, b1, h_buf, 2048, H_);
    gemm256<0, 0, 1><<<dim3(H_ / 256, M / 256), 512, 0, stream>>>(
        h_buf, wb_w2, 2048, FF_, nullptr, out, H_, 2048);
    gemm256<1, 1, 0><<<dim3(2048 / 256, M / 256), 512, 0, stream>>>(
        z, wb_w1 + (size_t)2048 * H_, H_, H_, b1 + 2048, h_buf, 2048, H_);
    gemm256<0, 1, 1><<<dim3(H_ / 256, M / 256), 512, 0, stream>>>(
        h_buf, wb_w2 + 2048, 2048, FF_, b2, out, H_, 2048);
}

// Round 7
// 745.981 us; speedup vs baseline: 1.1583x; 1.1583x over previous
//
#include <hip/hip_runtime.h>
#include <cstdint>
#include <cstddef>

#define B_ 4
#define L_ 4096
#define H_ 1024
#define NH_ 16
#define W_ 64
#define SHIFT_ 32
#define FF_ 4096
#define HD_ 64

typedef unsigned short u16;
typedef __attribute__((ext_vector_type(8))) __bf16 bf16x8;
typedef __attribute__((ext_vector_type(4))) float f32x4;
typedef __attribute__((ext_vector_type(4))) unsigned short u16x4;

__device__ __forceinline__ float bf2f(u16 u) {
    unsigned int x = ((unsigned int)u) << 16;
    float f;
    __builtin_memcpy(&f, &x, 4);
    return f;
}
__device__ __forceinline__ u16 f2bf(float f) {
    unsigned int u;
    __builtin_memcpy(&u, &f, 4);
    u = (u + 0x7fffu + ((u >> 16) & 1u)) >> 16;  // RNE
    return (u16)u;
}

__device__ __forceinline__ void gload16(const u16* g, u16* l) {
    __builtin_amdgcn_global_load_lds(
        (const __attribute__((address_space(1))) void*)g,
        (__attribute__((address_space(3))) void*)l, 16, 0, 0);
}

__device__ __forceinline__ bf16x8 ldfrag(const u16* p) {
    uint4 v = *(const uint4*)p;  // ds_read_b128
    bf16x8 r;
    __builtin_memcpy(&r, &v, 16);
    return r;
}

__device__ __forceinline__ f32x4 mfma16(bf16x8 a, bf16x8 b, f32x4 c) {
    return __builtin_amdgcn_mfma_f32_16x16x32_bf16(a, b, c, 0, 0, 0);
}

// ---------------------------------------------------------------------------
// fp32 -> bf16 conversion, all four weight matrices in ONE dispatch
// ---------------------------------------------------------------------------
__global__ __launch_bounds__(256) void cvt4_kernel(
    const float* __restrict__ s0, u16* __restrict__ d0, int n0,
    const float* __restrict__ s1, u16* __restrict__ d1, int n1,
    const float* __restrict__ s2, u16* __restrict__ d2, int n2,
    const float* __restrict__ s3, u16* __restrict__ d3, int n3) {
    int j = blockIdx.x * 256 + threadIdx.x;
    const float* s;
    u16* d;
    if (j < n0) {
        s = s0; d = d0;
    } else {
        j -= n0;
        if (j < n1) {
            s = s1; d = d1;
        } else {
            j -= n1;
            if (j < n2) {
                s = s2; d = d2;
            } else {
                j -= n2;
                if (j >= n3) return;
                s = s3; d = d3;
            }
        }
    }
    const float4 v = ((const float4*)s)[j];
    u16x4 o;
    o[0] = f2bf(v.x); o[1] = f2bf(v.y);
    o[2] = f2bf(v.z); o[3] = f2bf(v.w);
    ((u16x4*)d)[j] = o;
}

// ---------------------------------------------------------------------------
// GEMM 256x256 tile, BK=64, 512 threads (8 waves, 2Mx4N).  [R3, verified]
// Phased schedule (T3+T4+T5): per K-tile, 4 phases of
//   { ds_read frag subtile; stage ONE half-tile (2x global_load_lds);
//     s_barrier; lgkmcnt(0)+sched_barrier; setprio(1); 16 MFMA; setprio(0);
//     s_barrier }
// Counted vmcnt(4) ONCE per tile boundary (2 half-tiles stay in flight
// across tiles) -- never vmcnt(0) in the main loop; barriers are raw
// s_barrier (no drain). Stage map (race-free by barrier ordering):
//   p0: (t+1).Blo   p1: (t+1).Bhi    (other dbuf; its B-reads done at t-1.p3)
//   p2: (t+2).Alo   p3: (t+2).Ahi    (current dbuf; A-reads done at p1)
// A/B test history: 2-phase merge (R6) and 32x32 MFMA (R4) both LOSE --
// the fine 4-phase interleave is the lever (matches m196). Do not coarsen.
// LDS per dbuf: [256 rows][8 slots of 16B], slot' = slot ^ (row&7); linear
// DMA dest + inverse-swizzled global source (both-sides rule).
// XCD-aware chunked blockIdx swizzle (T1).
// Epilogue: acc -> LDS (dead staging buffers) -> coalesced dwordx4 stores;
//   F32OUT: C fp32 accumulated in place (C += result), 64B/quad RMW.
// ---------------------------------------------------------------------------
template <int GELU, int BIAS, int F32OUT>
__global__ __launch_bounds__(512, 2) void gemm256(
    const u16* __restrict__ A, const u16* __restrict__ Bm,
    int lda, int ldb, const float* __restrict__ bias,
    void* __restrict__ Cv, int N, int K) {
    __shared__ __align__(16) u16 sA0[16384];
    __shared__ __align__(16) u16 sA1[16384];
    __shared__ __align__(16) u16 sB0[16384];
    __shared__ __align__(16) u16 sB1[16384];

    const int tid = threadIdx.x;
    const int lane = tid & 63;
    const int wv = tid >> 6;
    const int wr = wv >> 2;      // 0..1  (M half: 128 rows)
    const int wc = wv & 3;       // 0..3  (N quarter: 64 cols)
    const int ln15 = lane & 15;
    const int quad = lane >> 4;  // 0..3

    // XCD-aware chunked swizzle (all our grids have nwg % 8 == 0)
    const int gX = gridDim.x;
    const int nwg = gX * gridDim.y;
    int lin = blockIdx.y * gX + blockIdx.x;
    if ((nwg & 7) == 0) lin = (lin & 7) * (nwg >> 3) + (lin >> 3);
    const int mBase = (lin / gX) * 256;
    const int nBase = (lin % gX) * 256;
    const int nt = K >> 6;  // 16 or 32 for our shapes

    // staging: thread -> (row srow, slot tid&7); global k-chunk inverse-
    // swizzled so the linear DMA dest yields the swizzled layout.
    const int srow = tid >> 3;                    // 0..63
    const int sk = ((tid & 7) ^ (srow & 7)) * 8;  // u16 units
    const u16* gA = A + (size_t)(mBase + srow) * lda + sk;
    const u16* gB = Bm + (size_t)(nBase + srow) * ldb + sk;

    // read offsets (u16 units): frag(f,kk) @ rb + f*1024 + swK
    const int rbA = (wr * 128 + ln15) * 64;
    const int rbB = (wc * 64 + ln15) * 64;
    const int sw0 = (quad ^ (ln15 & 7)) * 8;        // kk=0
    const int sw1 = ((4 + quad) ^ (ln15 & 7)) * 8;  // kk=1

    f32x4 acc[8][4] = {};

#define STG(gp, ld, buf, h, t)                                          \
    do {                                                                \
        const u16* _g = (gp) + (size_t)((h)*128) * (ld) + (t) * 64;     \
        u16* _d = (buf) + (h)*8192 + tid * 8;                           \
        gload16(_g, _d);                                                \
        gload16(_g + (size_t)64 * (ld), _d + 4096);                     \
    } while (0)
#define LGK0                                            \
    asm volatile("s_waitcnt lgkmcnt(0)" ::: "memory");  \
    __builtin_amdgcn_sched_barrier(0)
#define VMC4 asm volatile("s_waitcnt vmcnt(4)" ::: "memory")
#define BAR __builtin_amdgcn_s_barrier()

#define TILE_P(CA, CB, NB, tcur)                                        \
    do {                                                                \
        bf16x8 a0[8], a1[8], b0[4], b1[4];                              \
        /* p0: A(k0) x8 + B(k0) fn0-1; stage (t+1).Blo */               \
        _Pragma("unroll") for (int fm = 0; fm < 8; ++fm)                \
            a0[fm] = ldfrag((CA) + rbA + fm * 1024 + sw0);              \
        b0[0] = ldfrag((CB) + rbB + sw0);                               \
        b0[1] = ldfrag((CB) + rbB + 1024 + sw0);                        \
        if ((tcur) + 1 < nt) STG(gB, ldb, NB, 0, (tcur) + 1);           \
        BAR;                                                            \
        LGK0;                                                           \
        __builtin_amdgcn_s_setprio(1);                                  \
        _Pragma("unroll") for (int fm = 0; fm < 8; ++fm) {              \
            acc[fm][0] = mfma16(a0[fm], b0[0], acc[fm][0]);             \
            acc[fm][1] = mfma16(a0[fm], b0[1], acc[fm][1]);             \
        }                                                               \
        __builtin_amdgcn_s_setprio(0);                                  \
        BAR;                                                            \
        /* p1: B(k0) fn2-3 + A(k1) x8; stage (t+1).Bhi */               \
        b0[2] = ldfrag((CB) + rbB + 2048 + sw0);                        \
        b0[3] = ldfrag((CB) + rbB + 3072 + sw0);                        \
        _Pragma("unroll") for (int fm = 0; fm < 8; ++fm)                \
            a1[fm] = ldfrag((CA) + rbA + fm * 1024 + sw1);              \
        if ((tcur) + 1 < nt) STG(gB, ldb, NB, 1, (tcur) + 1);           \
        BAR;                                                            \
        LGK0;                                                           \
        __builtin_amdgcn_s_setprio(1);                                  \
        _Pragma("unroll") for (int fm = 0; fm < 8; ++fm) {              \
            acc[fm][2] = mfma16(a0[fm], b0[2], acc[fm][2]);             \
            acc[fm][3] = mfma16(a0[fm], b0[3], acc[fm][3]);             \
        }                                                               \
        __builtin_amdgcn_s_setprio(0);                                  \
        BAR;                                                            \
        /* p2: B(k1) fn0-1; stage (t+2).Alo (same dbuf, A-reads done) */ \
        b1[0] = ldfrag((CB) + rbB + sw1);                               \
        b1[1] = ldfrag((CB) + rbB + 1024 + sw1);                        \
        if ((tcur) + 2 < nt) STG(gA, lda, CA, 0, (tcur) + 2);           \
        BAR;                                                            \
        LGK0;                                                           \
        __builtin_amdgcn_s_setprio(1);                                  \
        _Pragma("unroll") for (int fm = 0; fm < 8; ++fm) {              \
            acc[fm][0] = mfma16(a1[fm], b1[0], acc[fm][0]);             \
            acc[fm][1] = mfma16(a1[fm], b1[1], acc[fm][1]);             \
        }                                                               \
        __builtin_amdgcn_s_setprio(0);                                  \
        BAR;                                                            \
        /* p3: B(k1) fn2-3; stage (t+2).Ahi */                          \
        b1[2] = ldfrag((CB) + rbB + 2048 + sw1);                        \
        b1[3] = ldfrag((CB) + rbB + 3072 + sw1);                        \
        if ((tcur) + 2 < nt) STG(gA, lda, CA, 1, (tcur) + 2);           \
        BAR;                                                            \
        LGK0;                                                           \
        __builtin_amdgcn_s_setprio(1);                                  \
        _Pragma("unroll") for (int fm = 0; fm < 8; ++fm) {              \
            acc[fm][2] = mfma16(a1[fm], b1[2], acc[fm][2]);             \
            acc[fm][3] = mfma16(a1[fm], b1[3], acc[fm][3]);             \
        }                                                               \
        __builtin_amdgcn_s_setprio(0);                                  \
        VMC4;                                                           \
        BAR;                                                            \
    } while (0)

    // prologue: t0.Alo t0.Ahi t0.Blo t0.Bhi t1.Alo t1.Ahi (12 loads);
    // vmcnt(4) -> tile 0 fully resident, t1.A may stay in flight.
    u16* mA = (u16*)sA0;  // non-const aliases for STG
    u16* mB = (u16*)sB0;
    STG(gA, lda, mA, 0, 0);
    STG(gA, lda, mA, 1, 0);
    STG(gB, ldb, mB, 0, 0);
    STG(gB, ldb, mB, 1, 0);
    STG(gA, lda, sA1, 0, 1);
    STG(gA, lda, sA1, 1, 1);
    VMC4;
    BAR;

    for (int t = 0; t < nt; t += 2) {
        TILE_P(sA0, sB0, sB1, t);
        TILE_P(sA1, sB1, sB0, t + 1);
    }

    if (F32OUT) {
        // fp32 accumulate in place: each quad writes 64B contiguous.
        float* C = (float*)Cv;
        const int r0 = mBase + wr * 128 + quad * 4;
        const int c0 = nBase + wc * 64 + ln15;
#pragma unroll
        for (int fn = 0; fn < 4; ++fn) {
            const int col = c0 + fn * 16;
            const float bcol = BIAS ? bias[col] : 0.0f;
#pragma unroll
            for (int fm = 0; fm < 8; ++fm) {
#pragma unroll
                for (int r = 0; r < 4; ++r) {
                    const int row = r0 + fm * 16 + r;
                    float v = acc[fm][fn][r] + bcol;
                    if (GELU) v = 0.5f * v * (1.0f + erff(v * 0.70710678118f));
                    C[(size_t)row * N + col] += v;
                }
            }
        }
    } else {
        // stage C tile in LDS (rows 0-63:sA0, 64-127:sA1, 128-191:sB0,
        // 192-255:sB1), then fully-coalesced dwordx4 stores.
        u16* lo = wr ? sB0 : sA0;  // fm 0..3
        u16* hi = wr ? sB1 : sA1;  // fm 4..7
#pragma unroll
        for (int fn = 0; fn < 4; ++fn) {
            const int col = wc * 64 + fn * 16 + ln15;
            const float bcol = BIAS ? bias[nBase + col] : 0.0f;
#pragma unroll
            for (int fm = 0; fm < 8; ++fm) {
                u16* wb = (fm < 4) ? lo : hi;
#pragma unroll
                for (int r = 0; r < 4; ++r) {
                    float v = acc[fm][fn][r] + bcol;
                    if (GELU) v = 0.5f * v * (1.0f + erff(v * 0.70710678118f));
                    wb[((fm & 3) * 16 + quad * 4 + r) * 256 + col] = f2bf(v);
                }
            }
        }
        __syncthreads();
        u16* Cu = (u16*)Cv;
        const int rr = tid >> 5;        // 0..15
        const int cc = (tid & 31) * 8;  // u16 units, 16B chunks
#pragma unroll
        for (int p = 0; p < 16; ++p) {
            const u16* rb = (p < 4) ? sA0 : (p < 8) ? sA1 : (p < 12) ? sB0 : sB1;
            const uint4 vv = *(const uint4*)(rb + ((p & 3) * 16 + rr) * 256 + cc);
            *(uint4*)(Cu + (size_t)(mBase + p * 16 + rr) * N + nBase + cc) = vv;
        }
    }
#undef TILE_P
#undef BAR
#undef VMC4
#undef LGK0
#undef STG
}

// ---------------------------------------------------------------------------
// LN1 (full M): y[r,:] = bf16( LN(x[bi,(l+SHIFT)%L,:]) * g + b ), fp32 input
// ---------------------------------------------------------------------------
__global__ __launch_bounds__(256, 4) void ln1_kernel(
    const float* __restrict__ x, const float* __restrict__ g,
    const float* __restrict__ bb, u16* __restrict__ y) {
    const int row = blockIdx.x;
    const int bi = row >> 12, l = row & 4095;
    const float* src = x + ((size_t)(bi << 12) + ((l + SHIFT_) & 4095)) * 1024;
    const int t = threadIdx.x;
    const int lane = t & 63, wv = t >> 6;

    const float4 u = ((const float4*)src)[t];
    float v[4] = {u.x, u.y, u.z, u.w};
    float sum = 0.f, sq = 0.f;
#pragma unroll
    for (int k = 0; k < 4; ++k) { sum += v[k]; sq += v[k] * v[k]; }
    for (int off = 32; off > 0; off >>= 1) {
        sum += __shfl_down(sum, off);
        sq += __shfl_down(sq, off);
    }
    __shared__ float red[8];
    __shared__ float smu, srs;
    if (lane == 0) { red[wv] = sum; red[4 + wv] = sq; }
    __syncthreads();
    if (t == 0) {
        float s = red[0] + red[1] + red[2] + red[3];
        float q = red[4] + red[5] + red[6] + red[7];
        float mu = s * (1.0f / 1024.0f);
        float var = q * (1.0f / 1024.0f) - mu * mu;
        smu = mu;
        srs = rsqrtf(var + 1e-5f);
    }
    __syncthreads();
    const float mu = smu, rs = srs;
    const float4 gv = ((const float4*)g)[t];
    const float4 bv = ((const float4*)bb)[t];
    u16x4 outv;
    outv[0] = f2bf((v[0] - mu) * rs * gv.x + bv.x);
    outv[1] = f2bf((v[1] - mu) * rs * gv.y + bv.y);
    outv[2] = f2bf((v[2] - mu) * rs * gv.z + bv.z);
    outv[3] = f2bf((v[3] - mu) * rs * gv.w + bv.w);
    ((u16x4*)(y + (size_t)row * 1024))[t] = outv;
}

// ---------------------------------------------------------------------------
// LN2 fused (full M): x2 = x + roll(o2,+32)  (fp32 -> d_out)
//                     z  = bf16( LN(x2)*g + b )
// ---------------------------------------------------------------------------
__global__ __launch_bounds__(256, 4) void ln2_kernel(
    const float* __restrict__ x, const u16* __restrict__ o2,
    const float* __restrict__ g, const float* __restrict__ bb,
    float* __restrict__ x2, u16* __restrict__ z) {
    const int row = blockIdx.x;
    const int bi = row >> 12, l = row & 4095;
    const size_t srcO = (size_t)(bi << 12) + ((l - SHIFT_) & 4095);
    const int t = threadIdx.x;
    const int lane = t & 63, wv = t >> 6;

    const float4 ux = ((const float4*)(x + (size_t)row * 1024))[t];
    const u16x4 uo = ((const u16x4*)(o2 + srcO * 1024))[t];
    float v[4];
    v[0] = ux.x + bf2f(uo[0]);
    v[1] = ux.y + bf2f(uo[1]);
    v[2] = ux.z + bf2f(uo[2]);
    v[3] = ux.w + bf2f(uo[3]);
    float sum = 0.f, sq = 0.f;
#pragma unroll
    for (int k = 0; k < 4; ++k) { sum += v[k]; sq += v[k] * v[k]; }
    float4 x2v = {v[0], v[1], v[2], v[3]};
    ((float4*)(x2 + (size_t)row * 1024))[t] = x2v;

    for (int off = 32; off > 0; off >>= 1) {
        sum += __shfl_down(sum, off);
        sq += __shfl_down(sq, off);
    }
    __shared__ float red[8];
    __shared__ float smu, srs;
    if (lane == 0) { red[wv] = sum; red[4 + wv] = sq; }
    __syncthreads();
    if (t == 0) {
        float s = red[0] + red[1] + red[2] + red[3];
        float q = red[4] + red[5] + red[6] + red[7];
        float mu = s * (1.0f / 1024.0f);
        float var = q * (1.0f / 1024.0f) - mu * mu;
        smu = mu;
        srs = rsqrtf(var + 1e-5f);
    }
    __syncthreads();
    const float mu = smu, rs = srs;
    const float4 gv = ((const float4*)g)[t];
    const float4 bv = ((const float4*)bb)[t];
    u16x4 outv;
    outv[0] = f2bf((v[0] - mu) * rs * gv.x + bv.x);
    outv[1] = f2bf((v[1] - mu) * rs * gv.y + bv.y);
    outv[2] = f2bf((v[2] - mu) * rs * gv.z + bv.z);
    outv[3] = f2bf((v[3] - mu) * rs * gv.w + bv.w);
    ((u16x4*)(z + (size_t)row * 1024))[t] = outv;
}

// ---------------------------------------------------------------------------
// Windowed attention (bf16 in/out): block = (window, head).
// 3 blocks/CU (LDS 41.5 KB x 3 = 124 KB; VGPR cap ~170 at 3 waves/EU).
// ---------------------------------------------------------------------------
__global__ __launch_bounds__(256, 3) void attn_kernel(
    const u16* __restrict__ qkv, u16* __restrict__ o) {
    __shared__ __align__(16) u16 sQ[64 * 64];  // reused as P
    __shared__ __align__(16) u16 sK[64 * 64];
    __shared__ __align__(16) u16 sV[64 * 64];
    __shared__ float sS[64 * 66];

    const int t = threadIdx.x;
    const int win = blockIdx.x >> 4;
    const int head = blockIdx.x & 15;
    const size_t rowbase = (size_t)win * 64;
    const u16* base = qkv + rowbase * 3072 + head * 64;

    {  // stage Q,K,V via global_load_lds: chunks c = t, t+256
        const int c0 = t, c1 = t + 256;
        const int r0 = c0 >> 3, d0 = (c0 & 7) * 8;
        const int r1 = c1 >> 3, d1 = (c1 & 7) * 8;
        const u16* g0 = base + (size_t)r0 * 3072 + d0;
        const u16* g1 = base + (size_t)r1 * 3072 + d1;
        gload16(g0, &sQ[c0 * 8]);
        gload16(g1, &sQ[c1 * 8]);
        gload16(g0 + 1024, &sK[c0 * 8]);
        gload16(g1 + 1024, &sK[c1 * 8]);
        gload16(g0 + 2048, &sV[c0 * 8]);
        gload16(g1 + 2048, &sV[c1 * 8]);
    }
    __syncthreads();

    const int lane = t & 63, wv = t >> 6;
    const int ln15 = lane & 15, quad = lane >> 4;

    f32x4 accS[4] = {};
#pragma unroll
    for (int kb = 0; kb < 2; ++kb) {
        bf16x8 aF = ldfrag(&sQ[(wv * 16 + ln15) * 64 + kb * 32 + quad * 8]);
#pragma unroll
        for (int jt = 0; jt < 4; ++jt) {
            bf16x8 bF = ldfrag(&sK[(jt * 16 + ln15) * 64 + kb * 32 + quad * 8]);
            accS[jt] = mfma16(aF, bF, accS[jt]);
        }
    }
#pragma unroll
    for (int jt = 0; jt < 4; ++jt)
#pragma unroll
        for (int r = 0; r < 4; ++r)
            sS[(wv * 16 + quad * 4 + r) * 66 + jt * 16 + ln15] =
                accS[jt][r] * 0.125f;
    __syncthreads();

    {
        const int row = t >> 2, part = t & 3;
        const float* sr = &sS[row * 66 + part * 16];
        float vals[16];
        float mx = -1e30f;
#pragma unroll
        for (int i = 0; i < 16; ++i) {
            vals[i] = sr[i];
            mx = fmaxf(mx, vals[i]);
        }
        mx = fmaxf(mx, __shfl_xor(mx, 1));
        mx = fmaxf(mx, __shfl_xor(mx, 2));
        float sum = 0.f;
#pragma unroll
        for (int i = 0; i < 16; ++i) {
            vals[i] = __expf(vals[i] - mx);
            sum += vals[i];
        }
        sum += __shfl_xor(sum, 1);
        sum += __shfl_xor(sum, 2);
        const float inv = 1.0f / sum;
        u16* pr = &sQ[row * 64 + part * 16];
#pragma unroll
        for (int i = 0; i < 16; ++i) pr[i] = f2bf(vals[i] * inv);
    }
    __syncthreads();

    f32x4 accO[4] = {};
#pragma unroll
    for (int kb = 0; kb < 2; ++kb) {
        bf16x8 aF = ldfrag(&sQ[(wv * 16 + ln15) * 64 + kb * 32 + quad * 8]);
#pragma unroll
        for (int dt = 0; dt < 4; ++dt) {
            u16 tmp[8];
#pragma unroll
            for (int j = 0; j < 8; ++j)
                tmp[j] = sV[(kb * 32 + quad * 8 + j) * 64 + dt * 16 + ln15];
            bf16x8 bF;
            __builtin_memcpy(&bF, tmp, 16);
            accO[dt] = mfma16(aF, bF, accO[dt]);
        }
    }
    u16* ob = o + rowbase * 1024 + head * 64;
#pragma unroll
    for (int dt = 0; dt < 4; ++dt)
#pragma unroll
        for (int r = 0; r < 4; ++r) {
            const int q = wv * 16 + quad * 4 + r;
            const int d = dt * 16 + ln15;
            ob[(size_t)q * 1024 + d] = f2bf(accO[dt][r]);
        }
}

// ---------------------------------------------------------------------------
extern "C" void kernel_launch(void* const* d_in, const int* in_sizes, int n_in,
                              void* d_out, int out_size, void* d_ws,
                              size_t ws_size, hipStream_t stream) {
    (void)in_sizes; (void)n_in; (void)out_size; (void)ws_size;
    const float* x = (const float*)d_in[0];
    const float* ln1_g = (const float*)d_in[1];
    const float* ln1_b = (const float*)d_in[2];
    const float* in_proj_w = (const float*)d_in[3];
    const float* in_proj_b = (const float*)d_in[4];
    const float* out_proj_w = (const float*)d_in[5];
    const float* out_proj_b = (const float*)d_in[6];
    const float* ln2_g = (const float*)d_in[7];
    const float* ln2_b = (const float*)d_in[8];
    const float* w1 = (const float*)d_in[9];
    const float* b1 = (const float*)d_in[10];
    const float* w2 = (const float*)d_in[11];
    const float* b2 = (const float*)d_in[12];
    float* out = (float*)d_out;

    // Workspace layout (120 MB high-water; evidence: ws >= 160 MB):
    //   [  0,  8M) w1 bf16 (persist)     [  8, 16M) w2 bf16 (persist)
    //   [ 16, 22M) inproj bf16 (A)       [ 22, 24M) outproj bf16 (A)
    //   [ 24,120M) qkv bf16 full M (A, 16384 x 3072)
    //   [ 88,120M) o2 bf16 full M (out_proj -> ln2; overlays dead qkv tail)
    //   [ 16, 48M) z bf16 full M (B -> C; overlays dead inproj/outproj/qkv)
    //   [ 48,112M) h_half bf16 (C, 16384 x 2048; overlays dead qkv/o2)
    // d_out doubles as scratch: phase A qin [0,32M) + o_full [32,64M) bf16;
    // phase B writes x2 fp32 over all of d_out; FF2 epilogue RMW-accumulates
    // the two FF halves (+b2 on the second) directly into it.
    char* ws = (char*)d_ws;
    const size_t MB = 1024 * 1024;
    u16* wb_w1 = (u16*)(ws + 0 * MB);
    u16* wb_w2 = (u16*)(ws + 8 * MB);
    u16* wb_inproj = (u16*)(ws + 16 * MB);
    u16* wb_outproj = (u16*)(ws + 22 * MB);
    u16* qkv = (u16*)(ws + 24 * MB);
    u16* o2 = (u16*)(ws + 88 * MB);
    u16* z = (u16*)(ws + 16 * MB);
    u16* h_buf = (u16*)(ws + 48 * MB);

    u16* qin = (u16*)d_out;                        // [0,32M) of d_out
    u16* o_full = (u16*)((char*)d_out + 32 * MB);  // [32,64M) of d_out
    float* x2 = out;

    const int M = B_ * L_;  // 16384

    // Prologue: weights fp32 -> bf16 (single fused dispatch)
    {
        const int n0 = FF_ * H_ / 4, n1 = H_ * FF_ / 4;
        const int n2 = 3 * H_ * H_ / 4, n3 = H_ * H_ / 4;
        const int ntot = n0 + n1 + n2 + n3;
        cvt4_kernel<<<(ntot + 255) / 256, 256, 0, stream>>>(
            w1, wb_w1, n0, w2, wb_w2, n1, in_proj_w, wb_inproj, n2,
            out_proj_w, wb_outproj, n3);
    }

    // Phase A (full M): ln1 -> qkv proj -> windowed attn -> out_proj
    ln1_kernel<<<M, 256, 0, stream>>>(x, ln1_g, ln1_b, qin);
    gemm256<0, 1, 0><<<dim3(3 * H_ / 256, M / 256), 512, 0, stream>>>(
        qin, wb_inproj, H_, H_, in_proj_b, qkv, 3 * H_, H_);
    attn_kernel<<<(M / W_) * NH_, 256, 0, stream>>>(qkv, o_full);
    gemm256<0, 1, 0><<<dim3(H_ / 256, M / 256), 512, 0, stream>>>(
        o_full, wb_outproj, H_, H_, out_proj_b, o2, H_, H_);

    // Phase B: x2 = x + roll(o2,+32) (fp32 -> d_out), z = bf16(LN2(x2))
    ln2_kernel<<<M, 256, 0, stream>>>(x, o2, ln2_g, ln2_b, x2, z);

    // Phase C: FFN split along hidden dim (2 halves of FF=2048), full M.
    //   FF1: h = gelu(z @ w1[hf]^T + b1[hf])   grid (8,64) = 512 blocks
    //   FF2: out += h @ w2[:,hf]^T (+b2 once)  grid (4,64) = 256 blocks, RMW
    gemm256<1, 1, 0><<<dim3(2048 / 256, M / 256), 512, 0, stream>>>(
        z, wb_w1, H_, H_, b1, h_buf, 2048, H_);
    gemm256<0, 0, 1><<<dim3(H_ / 256, M / 256), 512, 0, stream>>>(
        h_buf, wb_w2, 2048, FF_, nullptr, out, H_, 2048);
    gemm256<1, 1, 0><<<dim3(2048 / 256, M / 256), 512, 0, stream>>>(
        z, wb_w1 + (size_t)2048 * H_, H_, H_, b1 + 2048, h_buf, 2048, H_);
    gemm256<0, 1, 1><<<dim3(H_ / 256, M / 256), 512, 0, stream>>>(
        h_buf, wb_w2 + 2048, 2048, FF_, b2, out, H_, 2048);
}